// Round 1
// baseline (1096.681 us; speedup 1.0000x reference)
//
#include <hip/hip_runtime.h>
#include <hip/hip_bf16.h>

typedef __bf16 bf16;
typedef __bf16 bf16x8 __attribute__((ext_vector_type(8)));
typedef __bf16 bf16x4 __attribute__((ext_vector_type(4)));
typedef __bf16 bf16x2 __attribute__((ext_vector_type(2)));
typedef float f32x4 __attribute__((ext_vector_type(4)));
typedef float f32x2 __attribute__((ext_vector_type(2)));

#define BATCH 32
#define N_ID 1024
#define L_IN 512

static const long ACT_E = (long)BATCH * N_ID * L_IN;   // 16,777,216 elems per activation
static const long S_NL  = (long)N_ID * L_IN;           // 524288  (per-batch [1024,512] or [512,1024])
static const long S_TT  = (long)N_ID * N_ID;           // 1048576 (per-batch S, time/cross)
static const long S_SS2 = (long)L_IN * L_IN;           // 262144  (per-batch S, space)

__device__ __forceinline__ void gload16(const bf16* g, bf16* l)
{
    __builtin_amdgcn_global_load_lds((__attribute__((address_space(1))) void*)g,
                                     (__attribute__((address_space(3))) void*)l, 16, 0, 0);
}

// ---------------------------------------------------------------------------
// NT GEMM: C[m,n] = sum_k A[m,k]*B[n,k]  (lda=ldb=K, ldc=N), batched via z.
// EPI: 0 bf16=acc+biasCol[n]; 1 bf16=acc+biasRow[m]; 2 f32=acc*scale;
//      3 bf16=acc; 4 bf16=acc*scal2[0]+scal2[1];
//      5 f32=acc+ResF32[m,n]+biasCol[n]; 6 f32=acc+ResBF16[m,n]+biasCol[n]
// ---------------------------------------------------------------------------
template<int EPI>
__global__ __launch_bounds__(256, 2)
void gemm_nt(const bf16* __restrict__ A, const bf16* __restrict__ Bm, void* __restrict__ Cout,
             const float* __restrict__ biasCol, const float* __restrict__ biasRow,
             const void* __restrict__ Res, const float* __restrict__ scal2,
             float scale, int M, int N, int K,
             long sA, long sB, long sC, long sRes)
{
    __shared__ __align__(16) bf16 sAt[128 * 32];
    __shared__ __align__(16) bf16 sBt[128 * 32];

    const int t  = threadIdx.x;
    const int w  = t >> 6;
    const int l  = t & 63;
    const int wm = w >> 1, wn = w & 1;
    const long z  = blockIdx.z;
    const long m0 = (long)blockIdx.x * 128;
    const long n0 = (long)blockIdx.y * 128;

    const bf16* Ab = A + z * sA;
    const bf16* Bb = Bm + z * sB;

    const int ldRow = (w << 4) + (l >> 2);   // 0..63
    const int ldCol = (l & 3) << 3;          // 0/8/16/24
    const bf16* ga = Ab + (m0 + ldRow) * (long)K + ldCol;
    const bf16* gb = Bb + (n0 + ldRow) * (long)K + ldCol;
    const long rowStep = 64L * (long)K;

    bf16* lA0 = &sAt[(w << 9)];
    bf16* lA1 = &sAt[2048 + (w << 9)];
    bf16* lB0 = &sBt[(w << 9)];
    bf16* lB1 = &sBt[2048 + (w << 9)];

    f32x4 acc[4][4] = {};

    const int fr = l & 15;
    const int kg = l >> 4;

    for (int k0 = 0; k0 < K; k0 += 32) {
        gload16(ga + k0, lA0);
        gload16(ga + rowStep + k0, lA1);
        gload16(gb + k0, lB0);
        gload16(gb + rowStep + k0, lB1);
        __syncthreads();   // drains vmcnt before ds_read (m97 structure)
        bf16x8 af[4], bfv[4];
#pragma unroll
        for (int i = 0; i < 4; ++i)
            af[i] = *(const bf16x8*)&sAt[(wm * 64 + i * 16 + fr) * 32 + kg * 8];
#pragma unroll
        for (int j = 0; j < 4; ++j)
            bfv[j] = *(const bf16x8*)&sBt[(wn * 64 + j * 16 + fr) * 32 + kg * 8];
#pragma unroll
        for (int i = 0; i < 4; ++i)
#pragma unroll
            for (int j = 0; j < 4; ++j)
                acc[i][j] = __builtin_amdgcn_mfma_f32_16x16x32_bf16(af[i], bfv[j], acc[i][j], 0, 0, 0);
        __syncthreads();
    }

    float e0 = 0.f, e1 = 0.f;
    if constexpr (EPI == 4) { e0 = scal2[0]; e1 = scal2[1]; }

#pragma unroll
    for (int i = 0; i < 4; ++i) {
        const long rb = m0 + wm * 64 + i * 16 + kg * 4;
#pragma unroll
        for (int j = 0; j < 4; ++j) {
            const long cc = n0 + wn * 64 + j * 16 + fr;
#pragma unroll
            for (int r = 0; r < 4; ++r) {
                const long rr = rb + r;
                const float v = acc[i][j][r];
                const long idx = z * sC + rr * (long)N + cc;
                if constexpr (EPI == 0)      ((bf16*)Cout)[idx] = (bf16)(v + biasCol[cc]);
                else if constexpr (EPI == 1) ((bf16*)Cout)[idx] = (bf16)(v + biasRow[rr]);
                else if constexpr (EPI == 2) ((float*)Cout)[idx] = v * scale;
                else if constexpr (EPI == 3) ((bf16*)Cout)[idx] = (bf16)v;
                else if constexpr (EPI == 4) ((bf16*)Cout)[idx] = (bf16)(v * e0 + e1);
                else if constexpr (EPI == 5) ((float*)Cout)[idx] = v + ((const float*)Res)[z * sRes + rr * (long)N + cc] + biasCol[cc];
                else                         ((float*)Cout)[idx] = v + (float)((const bf16*)Res)[z * sRes + rr * (long)N + cc] + biasCol[cc];
            }
        }
    }
}

// ---------------------------------------------------------------------------
// Row softmax: fp32 in (scale pre-applied), bf16 out. One 256-thread block/row.
// ---------------------------------------------------------------------------
template<int W>
__global__ __launch_bounds__(256)
void softmax_rows(const float* __restrict__ S, bf16* __restrict__ P)
{
    constexpr int NV = W / 256;
    const long row = blockIdx.x;
    const int t = threadIdx.x;
    const float* src = S + row * (long)W + t * NV;
    bf16* dst = P + row * (long)W + t * NV;

    float v[NV];
    if constexpr (NV == 4) { f32x4 x = *(const f32x4*)src; v[0]=x[0]; v[1]=x[1]; v[2]=x[2]; v[3]=x[3]; }
    else                   { f32x2 x = *(const f32x2*)src; v[0]=x[0]; v[1]=x[1]; }

    float m = v[0];
#pragma unroll
    for (int i = 1; i < NV; ++i) m = fmaxf(m, v[i]);
#pragma unroll
    for (int o = 32; o > 0; o >>= 1) m = fmaxf(m, __shfl_xor(m, o));
    __shared__ float red[8];
    const int w = t >> 6, l = t & 63;
    if (l == 0) red[w] = m;
    __syncthreads();
    m = fmaxf(fmaxf(red[0], red[1]), fmaxf(red[2], red[3]));

    float s = 0.f;
#pragma unroll
    for (int i = 0; i < NV; ++i) { v[i] = __expf(v[i] - m); s += v[i]; }
#pragma unroll
    for (int o = 32; o > 0; o >>= 1) s += __shfl_xor(s, o);
    if (l == 0) red[4 + w] = s;
    __syncthreads();
    s = red[4] + red[5] + red[6] + red[7];
    const float inv = 1.f / s;

    if constexpr (NV == 4) {
        bf16x4 o4; 
#pragma unroll
        for (int i = 0; i < 4; ++i) o4[i] = (bf16)(v[i] * inv);
        *(bf16x4*)dst = o4;
    } else {
        bf16x2 o2;
#pragma unroll
        for (int i = 0; i < 2; ++i) o2[i] = (bf16)(v[i] * inv);
        *(bf16x2*)dst = o2;
    }
}

// ---------------------------------------------------------------------------
// LayerNorm over rows of 512 (f32 in). OUTBF=1 -> bf16 out, else f32 out.
// In-place safe for f32 (each thread writes only its own elements).
// ---------------------------------------------------------------------------
template<int OUTBF>
__global__ __launch_bounds__(128)
void ln_rows(const float* __restrict__ X, const float* __restrict__ g,
             const float* __restrict__ bta, void* __restrict__ out)
{
    const long row = blockIdx.x;
    const int t = threadIdx.x;
    f32x4 v = *(const f32x4*)(X + row * 512 + t * 4);
    float s1 = v[0] + v[1] + v[2] + v[3];
    float s2 = v[0]*v[0] + v[1]*v[1] + v[2]*v[2] + v[3]*v[3];
#pragma unroll
    for (int o = 32; o > 0; o >>= 1) { s1 += __shfl_xor(s1, o); s2 += __shfl_xor(s2, o); }
    __shared__ float r1[2], r2[2];
    const int w = t >> 6, l = t & 63;
    if (l == 0) { r1[w] = s1; r2[w] = s2; }
    __syncthreads();
    s1 = r1[0] + r1[1];
    s2 = r2[0] + r2[1];
    const float mean = s1 * (1.f / 512.f);
    const float var  = s2 * (1.f / 512.f) - mean * mean;
    const float rstd = rsqrtf(var + 1e-5f);
    const int c = t * 4;
    if constexpr (OUTBF) {
        bf16x4 o4;
#pragma unroll
        for (int k = 0; k < 4; ++k) o4[k] = (bf16)((v[k] - mean) * rstd * g[c + k] + bta[c + k]);
        *(bf16x4*)((bf16*)out + row * 512 + c) = o4;
    } else {
        f32x4 o4;
#pragma unroll
        for (int k = 0; k < 4; ++k) o4[k] = (v[k] - mean) * rstd * g[c + k] + bta[c + k];
        *(f32x4*)((float*)out + row * 512 + c) = o4;
    }
}

// ---------------------------------------------------------------------------
// x[B,N,L] f32 -> Xb bf16 [B,N,L] and xt bf16 [B,L,N]
// ---------------------------------------------------------------------------
__global__ __launch_bounds__(256)
void transpose_cvt(const float* __restrict__ x, bf16* __restrict__ Xb, bf16* __restrict__ xt)
{
    __shared__ bf16 tile[32][33];
    const int b = blockIdx.z;
    const int n0 = blockIdx.x * 32, l0 = blockIdx.y * 32;
    const long base = (long)b * N_ID * L_IN;
    const int tx = threadIdx.x, ty = threadIdx.y;
#pragma unroll
    for (int i = ty; i < 32; i += 8) {
        const long idx = base + (long)(n0 + i) * L_IN + l0 + tx;
        const bf16 s = (bf16)x[idx];
        Xb[idx] = s;
        tile[i][tx] = s;
    }
    __syncthreads();
#pragma unroll
    for (int i = ty; i < 32; i += 8)
        xt[base + (long)(l0 + i) * N_ID + n0 + tx] = tile[tx][i];
}

__global__ void cvt_bf16(const float* __restrict__ in, bf16* __restrict__ out, int n)
{
    const int i = blockIdx.x * 256 + threadIdx.x;
    if (i < n) out[i] = (bf16)in[i];
}

// Wo [512,512,1,8] -> bf16 [512,512], summed over head axis
__global__ void wo_sum(const float* __restrict__ Wo, bf16* __restrict__ out)
{
    const int i = blockIdx.x * 256 + threadIdx.x; // < 262144
    const float* p = Wo + (long)i * 8;
    float s = 0.f;
#pragma unroll
    for (int h = 0; h < 8; ++h) s += p[h];
    out[i] = (bf16)s;
}

__global__ void prep_scal(const float* __restrict__ W1, const float* __restrict__ b1, float* __restrict__ out)
{
    if (threadIdx.x == 0 && blockIdx.x == 0) {
        float s = 0.f;
        for (int h = 0; h < 8; ++h) s += W1[h];
        out[0] = s;
        out[1] = b1[0];
    }
}

// ---------------------------------------------------------------------------
static void launch_gemm(int epi, const bf16* A, const bf16* B, void* C,
                        const float* bc, const float* br, const void* res, const float* sc2,
                        float scale, int M, int N, int K,
                        long sA, long sB, long sC, long sRes, int batches, hipStream_t st)
{
    dim3 g(M / 128, N / 128, batches), blk(256);
    switch (epi) {
    case 0: gemm_nt<0><<<g, blk, 0, st>>>(A, B, C, bc, br, res, sc2, scale, M, N, K, sA, sB, sC, sRes); break;
    case 1: gemm_nt<1><<<g, blk, 0, st>>>(A, B, C, bc, br, res, sc2, scale, M, N, K, sA, sB, sC, sRes); break;
    case 2: gemm_nt<2><<<g, blk, 0, st>>>(A, B, C, bc, br, res, sc2, scale, M, N, K, sA, sB, sC, sRes); break;
    case 3: gemm_nt<3><<<g, blk, 0, st>>>(A, B, C, bc, br, res, sc2, scale, M, N, K, sA, sB, sC, sRes); break;
    case 4: gemm_nt<4><<<g, blk, 0, st>>>(A, B, C, bc, br, res, sc2, scale, M, N, K, sA, sB, sC, sRes); break;
    case 5: gemm_nt<5><<<g, blk, 0, st>>>(A, B, C, bc, br, res, sc2, scale, M, N, K, sA, sB, sC, sRes); break;
    default: gemm_nt<6><<<g, blk, 0, st>>>(A, B, C, bc, br, res, sc2, scale, M, N, K, sA, sB, sC, sRes); break;
    }
}

extern "C" void kernel_launch(void* const* d_in, const int* in_sizes, int n_in,
                              void* d_out, int out_size, void* d_ws, size_t ws_size,
                              hipStream_t stream)
{
    (void)in_sizes; (void)n_in; (void)out_size;

    const float* x   = (const float*)d_in[0];
    const float* tWq = (const float*)d_in[1];  const float* tbq = (const float*)d_in[2];
    const float* tWk = (const float*)d_in[3];  const float* tbk = (const float*)d_in[4];
    const float* tWv = (const float*)d_in[5];  const float* tbv = (const float*)d_in[6];
    const float* tWo = (const float*)d_in[7];  const float* tbo = (const float*)d_in[8];
    const float* tg  = (const float*)d_in[9];  const float* tb  = (const float*)d_in[10];
    const float* cWq = (const float*)d_in[11]; const float* cbq = (const float*)d_in[12];
    const float* cWk = (const float*)d_in[13]; const float* cbk = (const float*)d_in[14];
    const float* cWv = (const float*)d_in[15]; const float* cbv = (const float*)d_in[16];
    const float* cWo = (const float*)d_in[17]; const float* cbo = (const float*)d_in[18];
    const float* cg  = (const float*)d_in[19]; const float* cb  = (const float*)d_in[20];
    const float* sWq = (const float*)d_in[21]; const float* sbq = (const float*)d_in[22];
    const float* sWk = (const float*)d_in[23]; const float* sbk = (const float*)d_in[24];
    const float* sWv = (const float*)d_in[25]; const float* sbv = (const float*)d_in[26];
    const float* sW1 = (const float*)d_in[27]; const float* sb1 = (const float*)d_in[28];

    char* p = (char*)d_ws;
    auto alloc = [&](size_t bytes) -> char* {
        char* r = p; p += (bytes + 255) & ~(size_t)255; return r;
    };

    // bf16 weight copies
    bf16* WqT = (bf16*)alloc(262144 * 2);  bf16* WkT = (bf16*)alloc(262144 * 2);  bf16* WvT = (bf16*)alloc(262144 * 2);
    bf16* WqC = (bf16*)alloc(262144 * 2);  bf16* WkC = (bf16*)alloc(262144 * 2);  bf16* WvC = (bf16*)alloc(262144 * 2);
    bf16* WqS = (bf16*)alloc(1048576 * 2); bf16* WkS = (bf16*)alloc(1048576 * 2); bf16* WvS = (bf16*)alloc(1048576 * 2);
    bf16* WsT = (bf16*)alloc(262144 * 2);  bf16* WsC = (bf16*)alloc(262144 * 2);
    float* scal = (float*)alloc(256);

    // activations (bf16, 33.55 MB each)
    const size_t ACT_B = (size_t)ACT_E * 2;
    bf16* Xb   = (bf16*)alloc(ACT_B);   // also reused as SO after stage T
    bf16* xt   = (bf16*)alloc(ACT_B);
    bf16* bufQ = (bf16*)alloc(ACT_B);   // Q / Qs / Qc; Lm aliases this in attn loops
    bf16* bufK = (bf16*)alloc(ACT_B);
    bf16* bufV = (bf16*)alloc(ACT_B);
    bf16* TO   = (bf16*)alloc(ACT_B);

    // adaptive attention chunking (S fp32 + P bf16 per chunk)
    size_t used = (size_t)(p - (char*)d_ws);
    int CB = 32;
    while (CB > 1 && used + (size_t)CB * 1048576ULL * 6ULL + 4096 > ws_size) CB >>= 1;
    float* Sbuf = (float*)alloc((size_t)CB * 1048576ULL * 4ULL);
    bf16*  Pbuf = (bf16*)alloc((size_t)CB * 1048576ULL * 2ULL);

    const float rsc_t = 0.08838834764831845f;  // 1/sqrt(1024/8)
    const float rsc_s = 0.125f;                // 1/sqrt(512/8)

    // ---- prep ----
    cvt_bf16<<<dim3(1024), dim3(256), 0, stream>>>(tWq, WqT, 262144);
    cvt_bf16<<<dim3(1024), dim3(256), 0, stream>>>(tWk, WkT, 262144);
    cvt_bf16<<<dim3(1024), dim3(256), 0, stream>>>(tWv, WvT, 262144);
    cvt_bf16<<<dim3(1024), dim3(256), 0, stream>>>(cWq, WqC, 262144);
    cvt_bf16<<<dim3(1024), dim3(256), 0, stream>>>(cWk, WkC, 262144);
    cvt_bf16<<<dim3(1024), dim3(256), 0, stream>>>(cWv, WvC, 262144);
    cvt_bf16<<<dim3(4096), dim3(256), 0, stream>>>(sWq, WqS, 1048576);
    cvt_bf16<<<dim3(4096), dim3(256), 0, stream>>>(sWk, WkS, 1048576);
    cvt_bf16<<<dim3(4096), dim3(256), 0, stream>>>(sWv, WvS, 1048576);
    wo_sum<<<dim3(1024), dim3(256), 0, stream>>>(tWo, WsT);
    wo_sum<<<dim3(1024), dim3(256), 0, stream>>>(cWo, WsC);
    prep_scal<<<dim3(1), dim3(64), 0, stream>>>(sW1, sb1, scal);
    transpose_cvt<<<dim3(32, 16, BATCH), dim3(32, 8), 0, stream>>>(x, Xb, xt);

    // time/cross attention core: S = Q@K^T*rsc -> softmax -> Lm = P@Vt^T (Lm aliases Q)
    auto attn_tc = [&](const bf16* Q, const bf16* Kb, const bf16* V, bf16* LmOut, float rsc) {
        for (int c0 = 0; c0 < BATCH; c0 += CB) {
            const long off = (long)c0 * S_NL;
            launch_gemm(2, Q + off, Kb + off, Sbuf, nullptr, nullptr, nullptr, nullptr, rsc,
                        1024, 1024, 512, S_NL, S_NL, S_TT, 0, CB, stream);
            softmax_rows<1024><<<dim3(CB * 1024), dim3(256), 0, stream>>>(Sbuf, Pbuf);
            launch_gemm(3, Pbuf, V + off, LmOut + off, nullptr, nullptr, nullptr, nullptr, 0.f,
                        1024, 512, 1024, S_TT, S_NL, S_NL, 0, CB, stream);
        }
    };

    // ==== Stage T (time de_att) ====
    launch_gemm(0, Xb, WqT, bufQ, tbq, nullptr, nullptr, nullptr, 0.f, 32768, 512, 512, 0, 0, 0, 0, 1, stream);
    launch_gemm(0, Xb, WkT, bufK, tbk, nullptr, nullptr, nullptr, 0.f, 32768, 512, 512, 0, 0, 0, 0, 1, stream);
    launch_gemm(1, WvT, Xb, bufV, nullptr, tbv, nullptr, nullptr, 0.f, 512, 1024, 512, 0, S_NL, S_NL, 0, BATCH, stream);
    attn_tc(bufQ, bufK, bufV, bufQ, rsc_t);
    launch_gemm(5, bufQ, WsT, d_out, tbo, nullptr, x, nullptr, 0.f, 32768, 512, 512, 0, 0, 0, 0, 1, stream);
    ln_rows<1><<<dim3(32768), dim3(128), 0, stream>>>((const float*)d_out, tg, tb, TO);

    // ==== Stage S (space attention) ====
    bf16* SOp = Xb;  // Xb dead after stage T projections -> reuse for space_out
    launch_gemm(0, xt, WqS, bufQ, sbq, nullptr, nullptr, nullptr, 0.f, 16384, 1024, 1024, 0, 0, 0, 0, 1, stream);
    launch_gemm(0, xt, WkS, bufK, sbk, nullptr, nullptr, nullptr, 0.f, 16384, 1024, 1024, 0, 0, 0, 0, 1, stream);
    launch_gemm(1, WvS, xt, bufV, nullptr, sbv, nullptr, nullptr, 0.f, 1024, 512, 1024, 0, S_NL, S_NL, 0, BATCH, stream);
    for (int c0 = 0; c0 < BATCH; c0 += CB) {
        const long off = (long)c0 * S_NL;
        launch_gemm(2, bufQ + off, bufK + off, Sbuf, nullptr, nullptr, nullptr, nullptr, rsc_s,
                    512, 512, 1024, S_NL, S_NL, S_SS2, 0, CB, stream);
        softmax_rows<512><<<dim3(CB * 512), dim3(256), 0, stream>>>(Sbuf, Pbuf);
        launch_gemm(4, bufV + off, Pbuf, SOp + off, nullptr, nullptr, nullptr, scal, 0.f,
                    1024, 512, 512, S_NL, S_SS2, S_NL, 0, CB, stream);
    }

    // ==== Stage C (cross de_att) ====
    launch_gemm(0, SOp, WqC, bufQ, cbq, nullptr, nullptr, nullptr, 0.f, 32768, 512, 512, 0, 0, 0, 0, 1, stream);
    launch_gemm(0, TO, WkC, bufK, cbk, nullptr, nullptr, nullptr, 0.f, 32768, 512, 512, 0, 0, 0, 0, 1, stream);
    launch_gemm(1, WvC, TO, bufV, nullptr, cbv, nullptr, nullptr, 0.f, 512, 1024, 512, 0, S_NL, S_NL, 0, BATCH, stream);
    attn_tc(bufQ, bufK, bufV, bufQ, rsc_t);
    launch_gemm(6, bufQ, WsC, d_out, cbo, nullptr, TO, nullptr, 0.f, 32768, 512, 512, 0, 0, 0, 0, 1, stream);
    ln_rows<0><<<dim3(32768), dim3(128), 0, stream>>>((const float*)d_out, cg, cb, d_out);
}